// Round 1
// baseline (131.026 us; speedup 1.0000x reference)
//
#include <hip/hip_runtime.h>

#define HH 192
#define WW 192
#define BB 2
#define NC 6
#define NF 3
#define FSZ 11
#define PAD 5
#define TW 16
#define TH 8
#define SWD (TW + 2*PAD)   // 26 staged cols
#define SHT (TH + 2*PAD)   // 18 staged rows
#define LDW (SWD + 2)      // 28: padded LDS row stride (even, non-pow2)
#define HW (HH*WW)

// One mean-field iteration, fully fused:
//   stage tile+halo of q=softmax(xsrc) and features into LDS,
//   121-tap joint bilateral filter, x_new = unary + msg,
//   LAST: write log_softmax(x_new) instead.
template<bool LAST>
__global__ __launch_bounds__(64)
void crf_iter(const float* __restrict__ xsrc, const float* __restrict__ xun,
              const float* __restrict__ feats, const float* __restrict__ spac,
              const float* __restrict__ swp, const float* __restrict__ awp,
              const float* __restrict__ isbp, const float* __restrict__ iabp,
              float* __restrict__ dst)
{
    __shared__ float q_lds[NC][SHT][LDW];
    __shared__ float f_lds[NF][SHT][LDW];
    __shared__ float sfw[FSZ*FSZ];
    __shared__ float sfa[FSZ*FSZ];

    const int tid = threadIdx.x;
    const int tx = tid & 7;
    const int ty = tid >> 3;
    const int b  = blockIdx.z;
    const int w0 = blockIdx.x * TW;
    const int h0 = blockIdx.y * TH;

    const float sw  = swp[0];
    const float aw  = awp[0];
    const float isb = isbp[0];
    const float iab = iabp[0];
    const float s0  = spac[b*2 + 0];
    const float s1  = spac[b*2 + 1];
    const float kapp = -0.5f * iab * iab;

    // spatial (smoothing) filter: sf = exp(-0.5*isb^2*((ri*s0)^2+(rj*s1)^2)), center=0
    for (int t = tid; t < FSZ*FSZ; t += 64) {
        const int fi = t / FSZ;
        const int fj = t - fi*FSZ;
        const float ri = (float)(fi - PAD) * s0 * isb;
        const float rj = (float)(fj - PAD) * s1 * isb;
        float sf = __expf(-0.5f * (ri*ri + rj*rj));
        if (fi == PAD && fj == PAD) sf = 0.0f;
        sfw[t] = sf * sw;   // smoothing_weight * sf
        sfa[t] = sf * aw;   // appearance_weight * sf
    }

    const float* xb = xsrc  + (size_t)b * NC * HW;
    const float* fb = feats + (size_t)b * NF * HW;

    // stage q = softmax(x) and features for tile + 5-halo; zeros outside image
    for (int idx = tid; idx < SHT*SWD; idx += 64) {
        const int sr = idx / SWD;
        const int sc = idx - sr*SWD;
        const int gh = h0 + sr - PAD;
        const int gw = w0 + sc - PAD;
        float q0=0.f,q1=0.f,q2=0.f,q3=0.f,q4=0.f,q5=0.f,g0=0.f,g1=0.f,g2=0.f;
        if (gh >= 0 && gh < HH && gw >= 0 && gw < WW) {
            const int off = gh*WW + gw;
            const float v0 = xb[off];
            const float v1 = xb[off +   HW];
            const float v2 = xb[off + 2*HW];
            const float v3 = xb[off + 3*HW];
            const float v4 = xb[off + 4*HW];
            const float v5 = xb[off + 5*HW];
            float m = fmaxf(fmaxf(fmaxf(v0,v1),fmaxf(v2,v3)),fmaxf(v4,v5));
            q0 = __expf(v0-m); q1 = __expf(v1-m); q2 = __expf(v2-m);
            q3 = __expf(v3-m); q4 = __expf(v4-m); q5 = __expf(v5-m);
            const float rs = 1.0f / (q0+q1+q2+q3+q4+q5);
            q0*=rs; q1*=rs; q2*=rs; q3*=rs; q4*=rs; q5*=rs;
            g0 = fb[off]; g1 = fb[off+HW]; g2 = fb[off+2*HW];
        }
        q_lds[0][sr][sc]=q0; q_lds[1][sr][sc]=q1; q_lds[2][sr][sc]=q2;
        q_lds[3][sr][sc]=q3; q_lds[4][sr][sc]=q4; q_lds[5][sr][sc]=q5;
        f_lds[0][sr][sc]=g0; f_lds[1][sr][sc]=g1; f_lds[2][sr][sc]=g2;
    }
    __syncthreads();

    // each thread: 2 horizontal pixels (lr, lc0) and (lr, lc0+1)
    const int lr  = ty;
    const int lc0 = tx*2;

    float msgA[NC], msgB[NC];
    #pragma unroll
    for (int c = 0; c < NC; ++c) { msgA[c]=0.f; msgB[c]=0.f; }

    const float fA0 = f_lds[0][lr+PAD][lc0+PAD];
    const float fA1 = f_lds[1][lr+PAD][lc0+PAD];
    const float fA2 = f_lds[2][lr+PAD][lc0+PAD];
    const float fB0 = f_lds[0][lr+PAD][lc0+PAD+1];
    const float fB1 = f_lds[1][lr+PAD][lc0+PAD+1];
    const float fB2 = f_lds[2][lr+PAD][lc0+PAD+1];

    #pragma unroll 1
    for (int i = 0; i < FSZ; ++i) {
        const int r = lr + i;
        const float* srw = &sfw[i*FSZ];
        const float* sra = &sfa[i*FSZ];
        #pragma unroll
        for (int a = 0; a < FSZ+1; ++a) {   // 12-col sliding window serves both pixels
            const int cc = lc0 + a;
            const float v0 = q_lds[0][r][cc];
            const float v1 = q_lds[1][r][cc];
            const float v2 = q_lds[2][r][cc];
            const float v3 = q_lds[3][r][cc];
            const float v4 = q_lds[4][r][cc];
            const float v5 = q_lds[5][r][cc];
            const float g0 = f_lds[0][r][cc];
            const float g1 = f_lds[1][r][cc];
            const float g2 = f_lds[2][r][cc];
            if (a < FSZ) {          // pixel A, tap j = a
                const float d0 = fA0-g0, d1 = fA1-g1, d2 = fA2-g2;
                const float t  = fmaf(d2,d2, fmaf(d1,d1, d0*d0));
                const float af = __expf(t * kapp);
                const float tf = fmaf(af, sra[a], srw[a]);
                msgA[0] = fmaf(tf, v0, msgA[0]);
                msgA[1] = fmaf(tf, v1, msgA[1]);
                msgA[2] = fmaf(tf, v2, msgA[2]);
                msgA[3] = fmaf(tf, v3, msgA[3]);
                msgA[4] = fmaf(tf, v4, msgA[4]);
                msgA[5] = fmaf(tf, v5, msgA[5]);
            }
            if (a >= 1) {           // pixel B, tap j = a-1
                const float d0 = fB0-g0, d1 = fB1-g1, d2 = fB2-g2;
                const float t  = fmaf(d2,d2, fmaf(d1,d1, d0*d0));
                const float af = __expf(t * kapp);
                const float tf = fmaf(af, sra[a-1], srw[a-1]);
                msgB[0] = fmaf(tf, v0, msgB[0]);
                msgB[1] = fmaf(tf, v1, msgB[1]);
                msgB[2] = fmaf(tf, v2, msgB[2]);
                msgB[3] = fmaf(tf, v3, msgB[3]);
                msgB[4] = fmaf(tf, v4, msgB[4]);
                msgB[5] = fmaf(tf, v5, msgB[5]);
            }
        }
    }

    // epilogue: x_new = unary + msg ; LAST -> log_softmax
    const int gh = h0 + lr;
    const int gcol = w0 + lc0;
    const size_t pbase = (size_t)b * NC * HW + (size_t)gh * WW + gcol;
    const float* up = xun + pbase;
    float* dp = dst + pbase;

    {   // pixel A
        float xn[NC];
        #pragma unroll
        for (int c = 0; c < NC; ++c) xn[c] = up[(size_t)c*HW] + msgA[c];
        if (LAST) {
            float m = xn[0];
            #pragma unroll
            for (int c = 1; c < NC; ++c) m = fmaxf(m, xn[c]);
            float s = 0.f;
            #pragma unroll
            for (int c = 0; c < NC; ++c) s += __expf(xn[c]-m);
            const float l = m + __logf(s);
            #pragma unroll
            for (int c = 0; c < NC; ++c) dp[(size_t)c*HW] = xn[c] - l;
        } else {
            #pragma unroll
            for (int c = 0; c < NC; ++c) dp[(size_t)c*HW] = xn[c];
        }
    }
    {   // pixel B
        float xn[NC];
        #pragma unroll
        for (int c = 0; c < NC; ++c) xn[c] = up[(size_t)c*HW + 1] + msgB[c];
        if (LAST) {
            float m = xn[0];
            #pragma unroll
            for (int c = 1; c < NC; ++c) m = fmaxf(m, xn[c]);
            float s = 0.f;
            #pragma unroll
            for (int c = 0; c < NC; ++c) s += __expf(xn[c]-m);
            const float l = m + __logf(s);
            #pragma unroll
            for (int c = 0; c < NC; ++c) dp[(size_t)c*HW + 1] = xn[c] - l;
        } else {
            #pragma unroll
            for (int c = 0; c < NC; ++c) dp[(size_t)c*HW + 1] = xn[c];
        }
    }
}

extern "C" void kernel_launch(void* const* d_in, const int* in_sizes, int n_in,
                              void* d_out, int out_size, void* d_ws, size_t ws_size,
                              hipStream_t stream)
{
    const float* x    = (const float*)d_in[0];
    const float* fts  = (const float*)d_in[1];
    const float* spc  = (const float*)d_in[2];
    const float* swp  = (const float*)d_in[3];
    const float* awp  = (const float*)d_in[4];
    const float* isbp = (const float*)d_in[5];
    const float* iabp = (const float*)d_in[6];
    float* out = (float*)d_out;
    float* wsb = (float*)d_ws;   // needs NC*HW*BB*4 = 1.77 MB

    dim3 grid(WW/TW, HH/TH, BB);   // 12 x 24 x 2 = 576 blocks
    dim3 blk(64);

    // ping-pong: x -> out -> ws -> out -> ws -> out(final, log_softmax)
    crf_iter<false><<<grid, blk, 0, stream>>>(x,   x, fts, spc, swp, awp, isbp, iabp, out);
    crf_iter<false><<<grid, blk, 0, stream>>>(out, x, fts, spc, swp, awp, isbp, iabp, wsb);
    crf_iter<false><<<grid, blk, 0, stream>>>(wsb, x, fts, spc, swp, awp, isbp, iabp, out);
    crf_iter<false><<<grid, blk, 0, stream>>>(out, x, fts, spc, swp, awp, isbp, iabp, wsb);
    crf_iter<true ><<<grid, blk, 0, stream>>>(wsb, x, fts, spc, swp, awp, isbp, iabp, out);
}

// Round 2
// 65.256 us; speedup vs baseline: 2.0079x; 2.0079x over previous
//
#include <hip/hip_runtime.h>

#define HH 192
#define WW 192
#define BB 2
#define NC 6
#define NF 3
#define FSZ 11
#define PAD 5
#define TW 16
#define TH 8
#define SWD (TW + 2*PAD)   // 26 staged cols
#define SHT (TH + 2*PAD)   // 18 staged rows
#define LDW 28             // LDS row stride (elements of float2 / float)
#define HW (HH*WW)
#define NGRP 4             // filter-row groups (waves) per tile

// One mean-field iteration, fully fused:
//   stage tile+halo of q=softmax(xsrc) (float2-packed channel pairs) and
//   features into LDS; 4 waves split the 11 filter rows (rows g, g+4, g+8);
//   partial messages reduced through LDS; x_new = unary + msg;
//   LAST -> log_softmax(x_new).
template<bool LAST>
__global__ __launch_bounds__(256)
void crf_iter(const float* __restrict__ xsrc, const float* __restrict__ xun,
              const float* __restrict__ feats, const float* __restrict__ spac,
              const float* __restrict__ swp, const float* __restrict__ awp,
              const float* __restrict__ isbp, const float* __restrict__ iabp,
              float* __restrict__ dst)
{
    __shared__ float2 qp[3][SHT][LDW];    // q channel pairs (01,23,45)
    __shared__ float2 f01[SHT][LDW];      // features ch 0,1
    __shared__ float  f2l[SHT][LDW];      // features ch 2
    __shared__ float  sfw[FSZ*FSZ];       // smoothing_weight * sf
    __shared__ float  sfa[FSZ*FSZ];       // appearance_weight * sf
    __shared__ float  pm[NGRP][64][12];   // partial msg: [group][pair][pxA 6 | pxB 6]

    const int tid = threadIdx.x;
    const int b  = blockIdx.z;
    const int w0 = blockIdx.x * TW;
    const int h0 = blockIdx.y * TH;

    const float sw  = swp[0];
    const float aw  = awp[0];
    const float isb = isbp[0];
    const float iab = iabp[0];
    const float s0  = spac[b*2 + 0];
    const float s1  = spac[b*2 + 1];
    const float kapp = -0.5f * iab * iab;

    // spatial filter tables
    for (int t = tid; t < FSZ*FSZ; t += 256) {
        const int fi = t / FSZ;
        const int fj = t - fi*FSZ;
        const float ri = (float)(fi - PAD) * s0 * isb;
        const float rj = (float)(fj - PAD) * s1 * isb;
        float sf = __expf(-0.5f * (ri*ri + rj*rj));
        if (fi == PAD && fj == PAD) sf = 0.0f;
        sfw[t] = sf * sw;
        sfa[t] = sf * aw;
    }

    const float* xb = xsrc  + (size_t)b * NC * HW;
    const float* fb = feats + (size_t)b * NF * HW;

    // stage q = softmax(x) and features for tile + 5-halo; zeros outside image
    for (int idx = tid; idx < SHT*SWD; idx += 256) {
        const int sr = idx / SWD;
        const int sc = idx - sr*SWD;
        const int gh = h0 + sr - PAD;
        const int gw = w0 + sc - PAD;
        float q0=0.f,q1=0.f,q2=0.f,q3=0.f,q4=0.f,q5=0.f,g0=0.f,g1=0.f,g2=0.f;
        if (gh >= 0 && gh < HH && gw >= 0 && gw < WW) {
            const int off = gh*WW + gw;
            const float v0 = xb[off];
            const float v1 = xb[off +   HW];
            const float v2 = xb[off + 2*HW];
            const float v3 = xb[off + 3*HW];
            const float v4 = xb[off + 4*HW];
            const float v5 = xb[off + 5*HW];
            float m = fmaxf(fmaxf(fmaxf(v0,v1),fmaxf(v2,v3)),fmaxf(v4,v5));
            q0 = __expf(v0-m); q1 = __expf(v1-m); q2 = __expf(v2-m);
            q3 = __expf(v3-m); q4 = __expf(v4-m); q5 = __expf(v5-m);
            const float rs = 1.0f / (q0+q1+q2+q3+q4+q5);
            q0*=rs; q1*=rs; q2*=rs; q3*=rs; q4*=rs; q5*=rs;
            g0 = fb[off]; g1 = fb[off+HW]; g2 = fb[off+2*HW];
        }
        qp[0][sr][sc] = make_float2(q0,q1);
        qp[1][sr][sc] = make_float2(q2,q3);
        qp[2][sr][sc] = make_float2(q4,q5);
        f01[sr][sc]   = make_float2(g0,g1);
        f2l[sr][sc]   = g2;
    }
    __syncthreads();

    // main loop: wave-group g handles filter rows g, g+4, g+8
    const int g   = tid >> 6;
    const int t64 = tid & 63;
    const int tx  = t64 & 7;
    const int ty  = t64 >> 3;
    const int lr  = ty;
    const int lc0 = tx*2;

    float msgA[NC], msgB[NC];
    #pragma unroll
    for (int c = 0; c < NC; ++c) { msgA[c]=0.f; msgB[c]=0.f; }

    const float2 fa01 = f01[lr+PAD][lc0+PAD];
    const float  fa2  = f2l[lr+PAD][lc0+PAD];
    const float2 fb01 = f01[lr+PAD][lc0+PAD+1];
    const float  fb2  = f2l[lr+PAD][lc0+PAD+1];

    #pragma unroll 1
    for (int ir = 0; ir < 3; ++ir) {
        const int i = g + 4*ir;          // filter row
        if (i >= FSZ) break;             // only g=3, ir=2
        const int r = lr + i;
        const float* srw = &sfw[i*FSZ];
        const float* sra = &sfa[i*FSZ];
        #pragma unroll
        for (int a = 0; a < FSZ+1; ++a) {   // 12-col sliding window, 2 px/thread
            const int cc = lc0 + a;
            const float2 q01 = qp[0][r][cc];
            const float2 q23 = qp[1][r][cc];
            const float2 q45 = qp[2][r][cc];
            const float2 g01 = f01[r][cc];
            const float  g2v = f2l[r][cc];
            if (a < FSZ) {          // pixel A, tap j = a
                const float d0 = fa01.x-g01.x, d1 = fa01.y-g01.y, d2 = fa2-g2v;
                const float t  = fmaf(d2,d2, fmaf(d1,d1, d0*d0));
                const float af = __expf(t * kapp);
                const float tf = fmaf(af, sra[a], srw[a]);
                msgA[0] = fmaf(tf, q01.x, msgA[0]);
                msgA[1] = fmaf(tf, q01.y, msgA[1]);
                msgA[2] = fmaf(tf, q23.x, msgA[2]);
                msgA[3] = fmaf(tf, q23.y, msgA[3]);
                msgA[4] = fmaf(tf, q45.x, msgA[4]);
                msgA[5] = fmaf(tf, q45.y, msgA[5]);
            }
            if (a >= 1) {           // pixel B, tap j = a-1
                const float d0 = fb01.x-g01.x, d1 = fb01.y-g01.y, d2 = fb2-g2v;
                const float t  = fmaf(d2,d2, fmaf(d1,d1, d0*d0));
                const float af = __expf(t * kapp);
                const float tf = fmaf(af, sra[a-1], srw[a-1]);
                msgB[0] = fmaf(tf, q01.x, msgB[0]);
                msgB[1] = fmaf(tf, q01.y, msgB[1]);
                msgB[2] = fmaf(tf, q23.x, msgB[2]);
                msgB[3] = fmaf(tf, q23.y, msgB[3]);
                msgB[4] = fmaf(tf, q45.x, msgB[4]);
                msgB[5] = fmaf(tf, q45.y, msgB[5]);
            }
        }
    }

    // store partial messages
    {
        float* pp = &pm[g][t64][0];
        #pragma unroll
        for (int c = 0; c < NC; ++c) { pp[c] = msgA[c]; pp[6+c] = msgB[c]; }
    }
    __syncthreads();

    // epilogue: 128 threads, one pixel each: reduce 4 partials, add unary, write
    if (tid < 128) {
        const int pair  = tid >> 1;
        const int which = tid & 1;
        float xn[NC];
        #pragma unroll
        for (int c = 0; c < NC; ++c) {
            xn[c] = pm[0][pair][which*6+c] + pm[1][pair][which*6+c]
                  + pm[2][pair][which*6+c] + pm[3][pair][which*6+c];
        }
        const int gh = h0 + (pair >> 3);
        const int gw = w0 + ((pair & 7) * 2) + which;
        const size_t pbase = (size_t)b * NC * HW + (size_t)gh * WW + gw;
        const float* up = xun + pbase;
        float* dp = dst + pbase;
        #pragma unroll
        for (int c = 0; c < NC; ++c) xn[c] += up[(size_t)c*HW];
        if (LAST) {
            float m = xn[0];
            #pragma unroll
            for (int c = 1; c < NC; ++c) m = fmaxf(m, xn[c]);
            float s = 0.f;
            #pragma unroll
            for (int c = 0; c < NC; ++c) s += __expf(xn[c]-m);
            const float l = m + __logf(s);
            #pragma unroll
            for (int c = 0; c < NC; ++c) dp[(size_t)c*HW] = xn[c] - l;
        } else {
            #pragma unroll
            for (int c = 0; c < NC; ++c) dp[(size_t)c*HW] = xn[c];
        }
    }
}

extern "C" void kernel_launch(void* const* d_in, const int* in_sizes, int n_in,
                              void* d_out, int out_size, void* d_ws, size_t ws_size,
                              hipStream_t stream)
{
    const float* x    = (const float*)d_in[0];
    const float* fts  = (const float*)d_in[1];
    const float* spc  = (const float*)d_in[2];
    const float* swp  = (const float*)d_in[3];
    const float* awp  = (const float*)d_in[4];
    const float* isbp = (const float*)d_in[5];
    const float* iabp = (const float*)d_in[6];
    float* out = (float*)d_out;
    float* wsb = (float*)d_ws;   // needs NC*HW*BB*4 = 1.77 MB

    dim3 grid(WW/TW, HH/TH, BB);   // 12 x 24 x 2 = 576 blocks
    dim3 blk(256);                 // 4 waves: filter-row groups

    // ping-pong: x -> out -> ws -> out -> ws -> out(final, log_softmax)
    crf_iter<false><<<grid, blk, 0, stream>>>(x,   x, fts, spc, swp, awp, isbp, iabp, out);
    crf_iter<false><<<grid, blk, 0, stream>>>(out, x, fts, spc, swp, awp, isbp, iabp, wsb);
    crf_iter<false><<<grid, blk, 0, stream>>>(wsb, x, fts, spc, swp, awp, isbp, iabp, out);
    crf_iter<false><<<grid, blk, 0, stream>>>(out, x, fts, spc, swp, awp, isbp, iabp, wsb);
    crf_iter<true ><<<grid, blk, 0, stream>>>(wsb, x, fts, spc, swp, awp, isbp, iabp, out);
}

// Round 4
// 65.245 us; speedup vs baseline: 2.0082x; 1.0002x over previous
//
#include <hip/hip_runtime.h>
#include <hip/hip_cooperative_groups.h>

namespace cg = cooperative_groups;

#define HH 192
#define WW 192
#define BB 2
#define NC 6
#define NF 3
#define FSZ 11
#define PAD 5
#define TW 16
#define TH 8
#define SWD (TW + 2*PAD)   // 26 staged cols
#define SHT (TH + 2*PAD)   // 18 staged rows
#define LDW 28             // LDS row stride (elements of float2 / float)
#define HW (HH*WW)
#define NGRP 4             // filter-row groups (waves) per tile
#define NITER 5
#define NBLK (12*24*2)     // 576 tiles

// ---------------- shared device routines (identical math to round-2 PASS) ---

__device__ __forceinline__ void build_sf_tables(int tid, float s0, float s1,
                                                float isb, float sw, float aw,
                                                float* sfw, float* sfa)
{
    for (int t = tid; t < FSZ*FSZ; t += 256) {
        const int fi = t / FSZ;
        const int fj = t - fi*FSZ;
        const float ri = (float)(fi - PAD) * s0 * isb;
        const float rj = (float)(fj - PAD) * s1 * isb;
        float sf = __expf(-0.5f * (ri*ri + rj*rj));
        if (fi == PAD && fj == PAD) sf = 0.0f;
        sfw[t] = sf * sw;
        sfa[t] = sf * aw;
    }
}

// ---------------- fused cooperative kernel (all 5 iterations) --------------

__global__ __launch_bounds__(256, 3)
void crf_fused(const float* __restrict__ x, const float* __restrict__ feats,
               const float* __restrict__ spac,
               const float* __restrict__ swp, const float* __restrict__ awp,
               const float* __restrict__ isbp, const float* __restrict__ iabp,
               float* __restrict__ ws0, float* __restrict__ ws1,
               float* __restrict__ out)
{
    __shared__ float2 qp[3][SHT][LDW];
    __shared__ float2 f01[SHT][LDW];
    __shared__ float  f2l[SHT][LDW];
    __shared__ float  sfw[FSZ*FSZ];
    __shared__ float  sfa[FSZ*FSZ];
    __shared__ float  pm[NGRP][64][12];

    cg::grid_group grid = cg::this_grid();

    const int tid = threadIdx.x;
    const int b  = blockIdx.z;
    const int w0 = blockIdx.x * TW;
    const int h0 = blockIdx.y * TH;

    const float sw  = swp[0];
    const float aw  = awp[0];
    const float isb = isbp[0];
    const float iab = iabp[0];
    const float s0  = spac[b*2 + 0];
    const float s1  = spac[b*2 + 1];
    const float kapp = -0.5f * iab * iab;

    build_sf_tables(tid, s0, s1, isb, sw, aw, sfw, sfa);

    const float* fb = feats + (size_t)b * NF * HW;
    for (int idx = tid; idx < SHT*SWD; idx += 256) {
        const int sr = idx / SWD;
        const int sc = idx - sr*SWD;
        const int gh = h0 + sr - PAD;
        const int gw = w0 + sc - PAD;
        float g0=0.f, g1=0.f, g2=0.f;
        if (gh >= 0 && gh < HH && gw >= 0 && gw < WW) {
            const int off = gh*WW + gw;
            g0 = fb[off]; g1 = fb[off+HW]; g2 = fb[off+2*HW];
        }
        f01[sr][sc] = make_float2(g0,g1);
        f2l[sr][sc] = g2;
    }

    const int g   = tid >> 6;
    const int t64 = tid & 63;
    const int tx  = t64 & 7;
    const int ty  = t64 >> 3;
    const int lr  = ty;
    const int lc0 = tx*2;

    __syncthreads();

    const float2 fa01 = f01[lr+PAD][lc0+PAD];
    const float  fa2  = f2l[lr+PAD][lc0+PAD];
    const float2 fb01 = f01[lr+PAD][lc0+PAD+1];
    const float  fb2  = f2l[lr+PAD][lc0+PAD+1];

    #pragma unroll 1
    for (int it = 0; it < NITER; ++it) {
        const float* src = (it == 0) ? x : ((it & 1) ? ws0 : ws1);
        float*       dst = (it == NITER-1) ? out : ((it & 1) ? ws1 : ws0);
        const bool  last = (it == NITER-1);

        const float* xb = src + (size_t)b * NC * HW;

        for (int idx = tid; idx < SHT*SWD; idx += 256) {
            const int sr = idx / SWD;
            const int sc = idx - sr*SWD;
            const int gh = h0 + sr - PAD;
            const int gw = w0 + sc - PAD;
            float q0=0.f,q1=0.f,q2=0.f,q3=0.f,q4=0.f,q5=0.f;
            if (gh >= 0 && gh < HH && gw >= 0 && gw < WW) {
                const int off = gh*WW + gw;
                const float v0 = xb[off];
                const float v1 = xb[off +   HW];
                const float v2 = xb[off + 2*HW];
                const float v3 = xb[off + 3*HW];
                const float v4 = xb[off + 4*HW];
                const float v5 = xb[off + 5*HW];
                float m = fmaxf(fmaxf(fmaxf(v0,v1),fmaxf(v2,v3)),fmaxf(v4,v5));
                q0 = __expf(v0-m); q1 = __expf(v1-m); q2 = __expf(v2-m);
                q3 = __expf(v3-m); q4 = __expf(v4-m); q5 = __expf(v5-m);
                const float rs = 1.0f / (q0+q1+q2+q3+q4+q5);
                q0*=rs; q1*=rs; q2*=rs; q3*=rs; q4*=rs; q5*=rs;
            }
            qp[0][sr][sc] = make_float2(q0,q1);
            qp[1][sr][sc] = make_float2(q2,q3);
            qp[2][sr][sc] = make_float2(q4,q5);
        }
        __syncthreads();

        float msgA[NC], msgB[NC];
        #pragma unroll
        for (int c = 0; c < NC; ++c) { msgA[c]=0.f; msgB[c]=0.f; }

        #pragma unroll 1
        for (int ir = 0; ir < 3; ++ir) {
            const int i = g + 4*ir;
            if (i >= FSZ) break;
            const int r = lr + i;
            const float* srw = &sfw[i*FSZ];
            const float* sra = &sfa[i*FSZ];
            #pragma unroll
            for (int a = 0; a < FSZ+1; ++a) {
                const int cc = lc0 + a;
                const float2 q01 = qp[0][r][cc];
                const float2 q23 = qp[1][r][cc];
                const float2 q45 = qp[2][r][cc];
                const float2 g01 = f01[r][cc];
                const float  g2v = f2l[r][cc];
                if (a < FSZ) {
                    const float d0 = fa01.x-g01.x, d1 = fa01.y-g01.y, d2 = fa2-g2v;
                    const float t  = fmaf(d2,d2, fmaf(d1,d1, d0*d0));
                    const float af = __expf(t * kapp);
                    const float tf = fmaf(af, sra[a], srw[a]);
                    msgA[0] = fmaf(tf, q01.x, msgA[0]);
                    msgA[1] = fmaf(tf, q01.y, msgA[1]);
                    msgA[2] = fmaf(tf, q23.x, msgA[2]);
                    msgA[3] = fmaf(tf, q23.y, msgA[3]);
                    msgA[4] = fmaf(tf, q45.x, msgA[4]);
                    msgA[5] = fmaf(tf, q45.y, msgA[5]);
                }
                if (a >= 1) {
                    const float d0 = fb01.x-g01.x, d1 = fb01.y-g01.y, d2 = fb2-g2v;
                    const float t  = fmaf(d2,d2, fmaf(d1,d1, d0*d0));
                    const float af = __expf(t * kapp);
                    const float tf = fmaf(af, sra[a-1], srw[a-1]);
                    msgB[0] = fmaf(tf, q01.x, msgB[0]);
                    msgB[1] = fmaf(tf, q01.y, msgB[1]);
                    msgB[2] = fmaf(tf, q23.x, msgB[2]);
                    msgB[3] = fmaf(tf, q23.y, msgB[3]);
                    msgB[4] = fmaf(tf, q45.x, msgB[4]);
                    msgB[5] = fmaf(tf, q45.y, msgB[5]);
                }
            }
        }

        {
            float* pp = &pm[g][t64][0];
            #pragma unroll
            for (int c = 0; c < NC; ++c) { pp[c] = msgA[c]; pp[6+c] = msgB[c]; }
        }
        __syncthreads();

        if (tid < 128) {
            const int pair  = tid >> 1;
            const int which = tid & 1;
            float xn[NC];
            #pragma unroll
            for (int c = 0; c < NC; ++c) {
                xn[c] = pm[0][pair][which*6+c] + pm[1][pair][which*6+c]
                      + pm[2][pair][which*6+c] + pm[3][pair][which*6+c];
            }
            const int gh = h0 + (pair >> 3);
            const int gw = w0 + ((pair & 7) * 2) + which;
            const size_t pbase = (size_t)b * NC * HW + (size_t)gh * WW + gw;
            const float* up = x + pbase;
            float* dp = dst + pbase;
            #pragma unroll
            for (int c = 0; c < NC; ++c) xn[c] += up[(size_t)c*HW];
            if (last) {
                float m = xn[0];
                #pragma unroll
                for (int c = 1; c < NC; ++c) m = fmaxf(m, xn[c]);
                float s = 0.f;
                #pragma unroll
                for (int c = 0; c < NC; ++c) s += __expf(xn[c]-m);
                const float l = m + __logf(s);
                #pragma unroll
                for (int c = 0; c < NC; ++c) dp[(size_t)c*HW] = xn[c] - l;
            } else {
                #pragma unroll
                for (int c = 0; c < NC; ++c) dp[(size_t)c*HW] = xn[c];
            }
        }

        if (it != NITER-1) grid.sync();
    }
}

// ---------------- fallback: round-2 proven single-iteration kernel ---------

template<bool LAST>
__global__ __launch_bounds__(256)
void crf_iter(const float* __restrict__ xsrc, const float* __restrict__ xun,
              const float* __restrict__ feats, const float* __restrict__ spac,
              const float* __restrict__ swp, const float* __restrict__ awp,
              const float* __restrict__ isbp, const float* __restrict__ iabp,
              float* __restrict__ dst)
{
    __shared__ float2 qp[3][SHT][LDW];
    __shared__ float2 f01[SHT][LDW];
    __shared__ float  f2l[SHT][LDW];
    __shared__ float  sfw[FSZ*FSZ];
    __shared__ float  sfa[FSZ*FSZ];
    __shared__ float  pm[NGRP][64][12];

    const int tid = threadIdx.x;
    const int b  = blockIdx.z;
    const int w0 = blockIdx.x * TW;
    const int h0 = blockIdx.y * TH;

    const float sw  = swp[0];
    const float aw  = awp[0];
    const float isb = isbp[0];
    const float iab = iabp[0];
    const float s0  = spac[b*2 + 0];
    const float s1  = spac[b*2 + 1];
    const float kapp = -0.5f * iab * iab;

    build_sf_tables(tid, s0, s1, isb, sw, aw, sfw, sfa);

    const float* xb = xsrc  + (size_t)b * NC * HW;
    const float* fb = feats + (size_t)b * NF * HW;

    for (int idx = tid; idx < SHT*SWD; idx += 256) {
        const int sr = idx / SWD;
        const int sc = idx - sr*SWD;
        const int gh = h0 + sr - PAD;
        const int gw = w0 + sc - PAD;
        float q0=0.f,q1=0.f,q2=0.f,q3=0.f,q4=0.f,q5=0.f,g0=0.f,g1=0.f,g2=0.f;
        if (gh >= 0 && gh < HH && gw >= 0 && gw < WW) {
            const int off = gh*WW + gw;
            const float v0 = xb[off];
            const float v1 = xb[off +   HW];
            const float v2 = xb[off + 2*HW];
            const float v3 = xb[off + 3*HW];
            const float v4 = xb[off + 4*HW];
            const float v5 = xb[off + 5*HW];
            float m = fmaxf(fmaxf(fmaxf(v0,v1),fmaxf(v2,v3)),fmaxf(v4,v5));
            q0 = __expf(v0-m); q1 = __expf(v1-m); q2 = __expf(v2-m);
            q3 = __expf(v3-m); q4 = __expf(v4-m); q5 = __expf(v5-m);
            const float rs = 1.0f / (q0+q1+q2+q3+q4+q5);
            q0*=rs; q1*=rs; q2*=rs; q3*=rs; q4*=rs; q5*=rs;
            g0 = fb[off]; g1 = fb[off+HW]; g2 = fb[off+2*HW];
        }
        qp[0][sr][sc] = make_float2(q0,q1);
        qp[1][sr][sc] = make_float2(q2,q3);
        qp[2][sr][sc] = make_float2(q4,q5);
        f01[sr][sc]   = make_float2(g0,g1);
        f2l[sr][sc]   = g2;
    }
    __syncthreads();

    const int g   = tid >> 6;
    const int t64 = tid & 63;
    const int tx  = t64 & 7;
    const int ty  = t64 >> 3;
    const int lr  = ty;
    const int lc0 = tx*2;

    float msgA[NC], msgB[NC];
    #pragma unroll
    for (int c = 0; c < NC; ++c) { msgA[c]=0.f; msgB[c]=0.f; }

    const float2 fa01 = f01[lr+PAD][lc0+PAD];
    const float  fa2  = f2l[lr+PAD][lc0+PAD];
    const float2 fb01 = f01[lr+PAD][lc0+PAD+1];
    const float  fb2  = f2l[lr+PAD][lc0+PAD+1];

    #pragma unroll 1
    for (int ir = 0; ir < 3; ++ir) {
        const int i = g + 4*ir;
        if (i >= FSZ) break;
        const int r = lr + i;
        const float* srw = &sfw[i*FSZ];
        const float* sra = &sfa[i*FSZ];
        #pragma unroll
        for (int a = 0; a < FSZ+1; ++a) {
            const int cc = lc0 + a;
            const float2 q01 = qp[0][r][cc];
            const float2 q23 = qp[1][r][cc];
            const float2 q45 = qp[2][r][cc];
            const float2 g01 = f01[r][cc];
            const float  g2v = f2l[r][cc];
            if (a < FSZ) {
                const float d0 = fa01.x-g01.x, d1 = fa01.y-g01.y, d2 = fa2-g2v;
                const float t  = fmaf(d2,d2, fmaf(d1,d1, d0*d0));
                const float af = __expf(t * kapp);
                const float tf = fmaf(af, sra[a], srw[a]);
                msgA[0] = fmaf(tf, q01.x, msgA[0]);
                msgA[1] = fmaf(tf, q01.y, msgA[1]);
                msgA[2] = fmaf(tf, q23.x, msgA[2]);
                msgA[3] = fmaf(tf, q23.y, msgA[3]);
                msgA[4] = fmaf(tf, q45.x, msgA[4]);
                msgA[5] = fmaf(tf, q45.y, msgA[5]);
            }
            if (a >= 1) {
                const float d0 = fb01.x-g01.x, d1 = fb01.y-g01.y, d2 = fb2-g2v;
                const float t  = fmaf(d2,d2, fmaf(d1,d1, d0*d0));
                const float af = __expf(t * kapp);
                const float tf = fmaf(af, sra[a-1], srw[a-1]);
                msgB[0] = fmaf(tf, q01.x, msgB[0]);
                msgB[1] = fmaf(tf, q01.y, msgB[1]);
                msgB[2] = fmaf(tf, q23.x, msgB[2]);
                msgB[3] = fmaf(tf, q23.y, msgB[3]);
                msgB[4] = fmaf(tf, q45.x, msgB[4]);
                msgB[5] = fmaf(tf, q45.y, msgB[5]);
            }
        }
    }

    {
        float* pp = &pm[g][t64][0];
        #pragma unroll
        for (int c = 0; c < NC; ++c) { pp[c] = msgA[c]; pp[6+c] = msgB[c]; }
    }
    __syncthreads();

    if (tid < 128) {
        const int pair  = tid >> 1;
        const int which = tid & 1;
        float xn[NC];
        #pragma unroll
        for (int c = 0; c < NC; ++c) {
            xn[c] = pm[0][pair][which*6+c] + pm[1][pair][which*6+c]
                  + pm[2][pair][which*6+c] + pm[3][pair][which*6+c];
        }
        const int gh = h0 + (pair >> 3);
        const int gw = w0 + ((pair & 7) * 2) + which;
        const size_t pbase = (size_t)b * NC * HW + (size_t)gh * WW + gw;
        const float* up = xun + pbase;
        float* dp = dst + pbase;
        #pragma unroll
        for (int c = 0; c < NC; ++c) xn[c] += up[(size_t)c*HW];
        if (LAST) {
            float m = xn[0];
            #pragma unroll
            for (int c = 1; c < NC; ++c) m = fmaxf(m, xn[c]);
            float s = 0.f;
            #pragma unroll
            for (int c = 0; c < NC; ++c) s += __expf(xn[c]-m);
            const float l = m + __logf(s);
            #pragma unroll
            for (int c = 0; c < NC; ++c) dp[(size_t)c*HW] = xn[c] - l;
        } else {
            #pragma unroll
            for (int c = 0; c < NC; ++c) dp[(size_t)c*HW] = xn[c];
        }
    }
}

extern "C" void kernel_launch(void* const* d_in, const int* in_sizes, int n_in,
                              void* d_out, int out_size, void* d_ws, size_t ws_size,
                              hipStream_t stream)
{
    const float* x    = (const float*)d_in[0];
    const float* fts  = (const float*)d_in[1];
    const float* spc  = (const float*)d_in[2];
    const float* swp  = (const float*)d_in[3];
    const float* awp  = (const float*)d_in[4];
    const float* isbp = (const float*)d_in[5];
    const float* iabp = (const float*)d_in[6];
    float* out = (float*)d_out;
    float* ws0 = (float*)d_ws;                        // slab 0: 1.77 MB
    float* ws1 = (float*)d_ws + (size_t)NC*HW*BB;     // slab 1: 1.77 MB

    dim3 grid(WW/TW, HH/TH, BB);   // 576 blocks
    dim3 blk(256);

    // deterministic co-residency check: need >= 3 blocks/CU for 576 on 256 CUs
    bool coop_ok = false;
    int maxb = 0;
    if (hipOccupancyMaxActiveBlocksPerMultiprocessor(&maxb, crf_fused, 256, 0)
            == hipSuccess && maxb * 256 >= NBLK) {
        void* args[] = { (void*)&x, (void*)&fts, (void*)&spc, (void*)&swp,
                         (void*)&awp, (void*)&isbp, (void*)&iabp,
                         (void*)&ws0, (void*)&ws1, (void*)&out };
        coop_ok = (hipLaunchCooperativeKernel((const void*)crf_fused, grid, blk,
                                              args, 0, stream) == hipSuccess);
    }

    if (!coop_ok) {
        // proven round-2 path: 5 single-iteration kernels, ping-pong
        crf_iter<false><<<grid, blk, 0, stream>>>(x,   x, fts, spc, swp, awp, isbp, iabp, out);
        crf_iter<false><<<grid, blk, 0, stream>>>(out, x, fts, spc, swp, awp, isbp, iabp, ws0);
        crf_iter<false><<<grid, blk, 0, stream>>>(ws0, x, fts, spc, swp, awp, isbp, iabp, out);
        crf_iter<false><<<grid, blk, 0, stream>>>(out, x, fts, spc, swp, awp, isbp, iabp, ws0);
        crf_iter<true ><<<grid, blk, 0, stream>>>(ws0, x, fts, spc, swp, awp, isbp, iabp, out);
    }
}

// Round 5
// 62.388 us; speedup vs baseline: 2.1002x; 1.0458x over previous
//
#include <hip/hip_runtime.h>

#define HH 192
#define WW 192
#define BB 2
#define NC 6
#define NF 3
#define FSZ 11
#define PAD 5
#define TW 16
#define TH 8
#define SWD (TW + 2*PAD)   // 26 staged cols
#define SHT (TH + 2*PAD)   // 18 staged rows
#define LQ 33              // qp row stride in float2  (33 % 16 == 1 -> conflict-free)
#define LF 33              // ff row stride in float4  (33 % 8  == 1 -> conflict-free)
#define HW (HH*WW)
#define NW 8               // waves per block
#define BT (NW*64)         // 512 threads

// One mean-field iteration per kernel.
//   FIRST: staging reads planar x and computes q=softmax(x) on the fly.
//   else : staging reads px-major q-slab (24B/px contiguous, written by prev kernel).
//   Epilogue: x_new = unary + msg;
//   LAST : writes planar log_softmax(x_new) to d_out.
//   else : writes px-major q=softmax(x_new) to the next q-slab.
template<bool FIRST, bool LAST>
__global__ __launch_bounds__(BT)
void crf_iter(const float* __restrict__ qsrc, const float* __restrict__ xun,
              const float* __restrict__ feats, const float* __restrict__ spac,
              const float* __restrict__ swp, const float* __restrict__ awp,
              const float* __restrict__ isbp, const float* __restrict__ iabp,
              float* __restrict__ dst)
{
    __shared__ float2 qp[3][SHT][LQ];     // q channel pairs (01,23,45)
    __shared__ float4 ff[SHT][LF];        // features (f0,f1,f2,-)
    __shared__ float  sfw[FSZ*FSZ];       // smoothing_weight * sf
    __shared__ float  sfa[FSZ*FSZ];       // appearance_weight * sf
    __shared__ float  pm[NW][12][65];     // partial msg [wave][which*6+c][pair]

    const int tid = threadIdx.x;
    const int b  = blockIdx.z;
    const int w0 = blockIdx.x * TW;
    const int h0 = blockIdx.y * TH;

    const float sw  = swp[0];
    const float aw  = awp[0];
    const float isb = isbp[0];
    const float iab = iabp[0];
    const float s0  = spac[b*2 + 0];
    const float s1  = spac[b*2 + 1];
    const float kapp = -0.5f * iab * iab;

    // spatial filter tables
    for (int t = tid; t < FSZ*FSZ; t += BT) {
        const int fi = t / FSZ;
        const int fj = t - fi*FSZ;
        const float ri = (float)(fi - PAD) * s0 * isb;
        const float rj = (float)(fj - PAD) * s1 * isb;
        float sf = __expf(-0.5f * (ri*ri + rj*rj));
        if (fi == PAD && fj == PAD) sf = 0.0f;
        sfw[t] = sf * sw;
        sfa[t] = sf * aw;
    }

    const float* fb = feats + (size_t)b * NF * HW;

    // stage q and features for tile + 5-halo; zeros outside image
    for (int idx = tid; idx < SHT*SWD; idx += BT) {
        const int sr = idx / SWD;
        const int sc = idx - sr*SWD;
        const int gh = h0 + sr - PAD;
        const int gw = w0 + sc - PAD;
        float q0=0.f,q1=0.f,q2=0.f,q3=0.f,q4=0.f,q5=0.f,g0=0.f,g1=0.f,g2=0.f;
        if (gh >= 0 && gh < HH && gw >= 0 && gw < WW) {
            const int off = gh*WW + gw;
            if (FIRST) {
                const float* xb = qsrc + (size_t)b * NC * HW;
                const float v0 = xb[off];
                const float v1 = xb[off +   HW];
                const float v2 = xb[off + 2*HW];
                const float v3 = xb[off + 3*HW];
                const float v4 = xb[off + 4*HW];
                const float v5 = xb[off + 5*HW];
                float m = fmaxf(fmaxf(fmaxf(v0,v1),fmaxf(v2,v3)),fmaxf(v4,v5));
                q0 = __expf(v0-m); q1 = __expf(v1-m); q2 = __expf(v2-m);
                q3 = __expf(v3-m); q4 = __expf(v4-m); q5 = __expf(v5-m);
                const float rs = 1.0f / (q0+q1+q2+q3+q4+q5);
                q0*=rs; q1*=rs; q2*=rs; q3*=rs; q4*=rs; q5*=rs;
            } else {
                const float2* qpx = (const float2*)(qsrc + ((size_t)(b*HH + gh)*WW + gw)*NC);
                const float2 a01 = qpx[0];
                const float2 a23 = qpx[1];
                const float2 a45 = qpx[2];
                q0=a01.x; q1=a01.y; q2=a23.x; q3=a23.y; q4=a45.x; q5=a45.y;
            }
            g0 = fb[off]; g1 = fb[off+HW]; g2 = fb[off+2*HW];
        }
        qp[0][sr][sc] = make_float2(q0,q1);
        qp[1][sr][sc] = make_float2(q2,q3);
        qp[2][sr][sc] = make_float2(q4,q5);
        ff[sr][sc]    = make_float4(g0,g1,g2,0.f);
    }

    // thread roles
    const int g   = tid >> 6;     // wave id: filter rows g, g+8
    const int t64 = tid & 63;
    const int tx  = t64 & 7;
    const int ty  = t64 >> 3;
    const int lr  = ty;
    const int lc0 = tx*2;

    __syncthreads();

    const float4 fa = ff[lr+PAD][lc0+PAD];
    const float4 fbx= ff[lr+PAD][lc0+PAD+1];

    float msgA[NC], msgB[NC];
    #pragma unroll
    for (int c = 0; c < NC; ++c) { msgA[c]=0.f; msgB[c]=0.f; }

    #pragma unroll 1
    for (int ir = 0; ir < 2; ++ir) {
        const int i = g + 8*ir;          // filter row
        if (i >= FSZ) break;
        const int r = lr + i;
        const float* srw = &sfw[i*FSZ];
        const float* sra = &sfa[i*FSZ];
        #pragma unroll
        for (int a = 0; a < FSZ+1; ++a) {   // 12-col sliding window, 2 px/thread
            const int cc = lc0 + a;
            const float2 q01 = qp[0][r][cc];
            const float2 q23 = qp[1][r][cc];
            const float2 q45 = qp[2][r][cc];
            const float4 gv  = ff[r][cc];
            if (a < FSZ) {          // pixel A, tap j = a
                const float d0 = fa.x-gv.x, d1 = fa.y-gv.y, d2 = fa.z-gv.z;
                const float t  = fmaf(d2,d2, fmaf(d1,d1, d0*d0));
                const float af = __expf(t * kapp);
                const float tf = fmaf(af, sra[a], srw[a]);
                msgA[0] = fmaf(tf, q01.x, msgA[0]);
                msgA[1] = fmaf(tf, q01.y, msgA[1]);
                msgA[2] = fmaf(tf, q23.x, msgA[2]);
                msgA[3] = fmaf(tf, q23.y, msgA[3]);
                msgA[4] = fmaf(tf, q45.x, msgA[4]);
                msgA[5] = fmaf(tf, q45.y, msgA[5]);
            }
            if (a >= 1) {           // pixel B, tap j = a-1
                const float d0 = fbx.x-gv.x, d1 = fbx.y-gv.y, d2 = fbx.z-gv.z;
                const float t  = fmaf(d2,d2, fmaf(d1,d1, d0*d0));
                const float af = __expf(t * kapp);
                const float tf = fmaf(af, sra[a-1], srw[a-1]);
                msgB[0] = fmaf(tf, q01.x, msgB[0]);
                msgB[1] = fmaf(tf, q01.y, msgB[1]);
                msgB[2] = fmaf(tf, q23.x, msgB[2]);
                msgB[3] = fmaf(tf, q23.y, msgB[3]);
                msgB[4] = fmaf(tf, q45.x, msgB[4]);
                msgB[5] = fmaf(tf, q45.y, msgB[5]);
            }
        }
    }

    // store partial messages (stride-1 across lanes -> conflict-free)
    #pragma unroll
    for (int c = 0; c < NC; ++c) {
        pm[g][c][t64]   = msgA[c];
        pm[g][6+c][t64] = msgB[c];
    }
    __syncthreads();

    // epilogue: 128 threads, one pixel each
    if (tid < 128) {
        const int pair  = tid >> 1;
        const int which = tid & 1;
        float xn[NC];
        #pragma unroll
        for (int c = 0; c < NC; ++c) {
            float s = 0.f;
            #pragma unroll
            for (int gr = 0; gr < NW; ++gr) s += pm[gr][which*6+c][pair];
            xn[c] = s;
        }
        const int gh = h0 + (pair >> 3);
        const int gw = w0 + ((pair & 7) * 2) + which;
        const size_t pbase = (size_t)b * NC * HW + (size_t)gh * WW + gw;
        const float* up = xun + pbase;
        #pragma unroll
        for (int c = 0; c < NC; ++c) xn[c] += up[(size_t)c*HW];

        float m = xn[0];
        #pragma unroll
        for (int c = 1; c < NC; ++c) m = fmaxf(m, xn[c]);

        if (LAST) {
            float s = 0.f;
            #pragma unroll
            for (int c = 0; c < NC; ++c) s += __expf(xn[c]-m);
            const float l = m + __logf(s);
            float* dp = dst + pbase;
            #pragma unroll
            for (int c = 0; c < NC; ++c) dp[(size_t)c*HW] = xn[c] - l;
        } else {
            float e[NC];
            float s = 0.f;
            #pragma unroll
            for (int c = 0; c < NC; ++c) { e[c] = __expf(xn[c]-m); s += e[c]; }
            const float rs = 1.0f / s;
            float2* qpx = (float2*)(dst + ((size_t)(b*HH + gh)*WW + gw)*NC);
            qpx[0] = make_float2(e[0]*rs, e[1]*rs);
            qpx[1] = make_float2(e[2]*rs, e[3]*rs);
            qpx[2] = make_float2(e[4]*rs, e[5]*rs);
        }
    }
}

extern "C" void kernel_launch(void* const* d_in, const int* in_sizes, int n_in,
                              void* d_out, int out_size, void* d_ws, size_t ws_size,
                              hipStream_t stream)
{
    const float* x    = (const float*)d_in[0];
    const float* fts  = (const float*)d_in[1];
    const float* spc  = (const float*)d_in[2];
    const float* swp  = (const float*)d_in[3];
    const float* awp  = (const float*)d_in[4];
    const float* isbp = (const float*)d_in[5];
    const float* iabp = (const float*)d_in[6];
    float* out = (float*)d_out;
    float* ws0 = (float*)d_ws;                        // q-slab 0: 1.77 MB (px-major)
    float* ws1 = (float*)d_ws + (size_t)NC*HW*BB;     // q-slab 1: 1.77 MB (px-major)

    dim3 grid(WW/TW, HH/TH, BB);   // 12 x 24 x 2 = 576 blocks
    dim3 blk(BT);                  // 512 threads = 8 waves

    crf_iter<true ,false><<<grid, blk, 0, stream>>>(x,   x, fts, spc, swp, awp, isbp, iabp, ws0);
    crf_iter<false,false><<<grid, blk, 0, stream>>>(ws0, x, fts, spc, swp, awp, isbp, iabp, ws1);
    crf_iter<false,false><<<grid, blk, 0, stream>>>(ws1, x, fts, spc, swp, awp, isbp, iabp, ws0);
    crf_iter<false,false><<<grid, blk, 0, stream>>>(ws0, x, fts, spc, swp, awp, isbp, iabp, ws1);
    crf_iter<false,true ><<<grid, blk, 0, stream>>>(ws1, x, fts, spc, swp, awp, isbp, iabp, out);
}